// Round 1
// baseline (828.760 us; speedup 1.0000x reference)
//
#include <hip/hip_runtime.h>
#include <math.h>

// Problem constants
constexpr int BQ = 32;       // query batch
constexpr int C  = 256;      // channels
constexpr int HW = 4096;     // 64*64
constexpr int W  = 64;
constexpr int P  = 256;      // protos (4 * 8 * 8)
constexpr float THRESH = 0.95f;
constexpr float SCALE  = 20.0f;
constexpr float EPSF   = 1e-4f;
constexpr double EPSD  = 1e-4;
constexpr float GAP_THRESH = 4e-3f;   // fp32 dist noise ~2e-5 -> 130x margin
constexpr int MAXSUS = 65536;

// d_out layout: pred [0, 131072) | debug_assign [131072, 262144) | proto_grid [262144, 278528)
constexpr int OUT_ASSIGN = BQ * HW;
constexpr int OUT_GRID   = 2 * BQ * HW;

// ---------------------------------------------------------------------------
// Prep: pooled protos (fp64 normalize), valid flags, proto_grid output,
// zero suspect counter. One block per proto, one thread per channel.
// ---------------------------------------------------------------------------
__global__ __launch_bounds__(256)
void prep_kernel(const float* __restrict__ sup_x, const float* __restrict__ sup_y,
                 float* __restrict__ out, float* __restrict__ pnT,
                 double* __restrict__ pn64, int* __restrict__ valid,
                 int* __restrict__ counter)
{
    const int p = blockIdx.x;     // proto index = s*64 + gy*8 + gx
    const int t = threadIdx.x;    // channel
    const int s = p >> 6, gy = (p >> 3) & 7, gx = p & 7;

    const float* base = sup_x + ((size_t)(s * C + t)) * HW + (gy * 8) * W + gx * 8;
    double sum = 0.0;
#pragma unroll
    for (int r = 0; r < 8; ++r) {
#pragma unroll
        for (int k = 0; k < 8; ++k) sum += (double)base[r * W + k];
    }
    const double mean = sum * (1.0 / 64.0);

    __shared__ double red[256];
    red[t] = mean * mean;
    __syncthreads();
    for (int off = 128; off > 0; off >>= 1) {
        if (t < off) red[t] += red[t + off];
        __syncthreads();
    }
    const double nrm = sqrt(red[0]);
    const double pnv = mean / fmax(nrm, EPSD);
    pnT[t * P + p] = (float)pnv;            // transposed fp32 copy: pnT[c][p]
    pn64[(size_t)p * C + t] = pnv;          // fp64 copy: pn64[p][c]

    __shared__ int cnt[64];
    if (t < 64) {
        const int r = t >> 3, k = t & 7;
        cnt[t] = (sup_y[s * HW + (gy * 8 + r) * W + gx * 8 + k] > THRESH) ? 1 : 0;
    }
    __syncthreads();
    if (t == 0) {
        int cs = 0;
        for (int i = 0; i < 64; ++i) cs += cnt[i];
        valid[p] = (cs > 32) ? 1 : 0;       // mask_pooled > 0.5  <=>  count > 32
        if (p == 0) *counter = 0;
    }
    // proto_grid output = mask_bin, flat order; block p covers 64 pixels
    if (t < 64) {
        const int i = p * 64 + t;
        out[OUT_GRID + i] = (sup_y[i] > THRESH) ? 1.0f : 0.0f;
    }
}

// ---------------------------------------------------------------------------
// Main: fp32 dists + fused softmax/argmax/pred. 32 positions per block.
// LDS: q-tile 32K + proto-chunk 64K + dists 32K (padded) ~= 133 KiB.
// ---------------------------------------------------------------------------
__global__ __launch_bounds__(256)
void dist_kernel(const float* __restrict__ qry, const float* __restrict__ pnT,
                 const int* __restrict__ valid, float* __restrict__ out,
                 int* __restrict__ counter, int* __restrict__ suspects)
{
    constexpr int J  = 32;    // positions per block
    constexpr int PC = 64;    // protos per chunk

    __shared__ float qs[C][J];            // 32 KiB, q tile (raw, unnormalized)
    __shared__ float pnc[C][PC];          // 64 KiB, proto chunk, c-major
    __shared__ float dists[J][P + 1];     // +1 pad: reduction reads stride P would be 32-way conflicted
    __shared__ float scale_s[J];
    __shared__ float redA[J][8];
    __shared__ float redB[J][8];
    __shared__ int   redI[J][8];
    __shared__ float finm[J];
    __shared__ int   validLds[P];

    const int t   = threadIdx.x;
    const int b   = blockIdx.x >> 7;          // / 128 tiles
    const int hw0 = (blockIdx.x & 127) * J;
    const float* qb = qry + (size_t)b * C * HW + hw0;

    validLds[t] = valid[t];

    // stage q tile: float4, 128B segments per channel row
    {
        const int j4 = (t & 7) * 4;
        const int c0 = t >> 3;
#pragma unroll
        for (int it = 0; it < 8; ++it) {
            const int c = c0 + it * 32;
            const float4 v = *(const float4*)(qb + (size_t)c * HW + j4);
            qs[c][j4 + 0] = v.x; qs[c][j4 + 1] = v.y;
            qs[c][j4 + 2] = v.z; qs[c][j4 + 3] = v.w;
        }
    }
    __syncthreads();

    const int j = t & 31;   // position
    const int g = t >> 5;   // group of 8 protos / reduction part

    // per-position scale = 20 / max(||q||, eps)  (common positive factor:
    // cannot change argmax ordering, and pred tolerance is loose -> fp32 ok)
    {
        float ss = 0.f;
        for (int c = g * 32; c < g * 32 + 32; ++c) { const float q = qs[c][j]; ss = fmaf(q, q, ss); }
        redA[j][g] = ss;
    }
    __syncthreads();
    if (t < J) {
        float ss = 0.f;
#pragma unroll
        for (int gg = 0; gg < 8; ++gg) ss += redA[t][gg];
        scale_s[t] = SCALE / fmaxf(sqrtf(ss), EPSF);
    }
    __syncthreads();

    for (int chunk = 0; chunk < 4; ++chunk) {
        const int pbase = chunk * PC;
        // stage proto chunk (c-major)
        {
            const int p4 = (t & 15) * 4;
            const int c0 = t >> 4;
#pragma unroll
            for (int it = 0; it < 16; ++it) {
                const int c = c0 + it * 16;
                const float4 v = *(const float4*)(pnT + c * P + pbase + p4);
                *(float4*)&pnc[c][p4] = v;
            }
        }
        __syncthreads();

        float acc[8] = {0.f, 0.f, 0.f, 0.f, 0.f, 0.f, 0.f, 0.f};
#pragma unroll 8
        for (int c = 0; c < C; ++c) {
            const float qv = qs[c][j];                       // conflict-free (lane=j)
            const float4 a  = *(const float4*)&pnc[c][g * 8];     // wave-uniform per half-wave
            const float4 bb = *(const float4*)&pnc[c][g * 8 + 4];
            acc[0] = fmaf(qv, a.x,  acc[0]); acc[1] = fmaf(qv, a.y,  acc[1]);
            acc[2] = fmaf(qv, a.z,  acc[2]); acc[3] = fmaf(qv, a.w,  acc[3]);
            acc[4] = fmaf(qv, bb.x, acc[4]); acc[5] = fmaf(qv, bb.y, acc[5]);
            acc[6] = fmaf(qv, bb.z, acc[6]); acc[7] = fmaf(qv, bb.w, acc[7]);
        }
        const float sc = scale_s[j];
#pragma unroll
        for (int i = 0; i < 8; ++i) dists[j][pbase + g * 8 + i] = acc[i] * sc;
        __syncthreads();   // pnc is overwritten next chunk
    }

    // pass 1: max / argmax (first occurrence) / second-max over valid protos
    {
        float m1 = -INFINITY, m2 = -INFINITY; int id = 0x7fffffff;
        const int p0 = g * 32;
        for (int p = p0; p < p0 + 32; ++p) {
            if (validLds[p]) {
                const float d = dists[j][p];
                if (d > m1)      { m2 = m1; m1 = d; id = p; }
                else if (d > m2) { m2 = d; }
            }
        }
        redA[j][g] = m1; redB[j][g] = m2; redI[j][g] = id;
    }
    __syncthreads();
    if (t < J) {
        float M1 = -INFINITY, M2 = -INFINITY; int ID = 0;
#pragma unroll
        for (int gg = 0; gg < 8; ++gg) {
            const float pm1 = redA[t][gg], pm2 = redB[t][gg];
            if (pm1 > M1) { M2 = fmaxf(M1, pm2); M1 = pm1; ID = redI[t][gg]; }
            else          { M2 = fmaxf(M2, pm1); }
        }
        finm[t] = M1;
        out[OUT_ASSIGN + b * HW + hw0 + t] = (float)ID;
        // near-tie -> exact fp64 recheck later (M2=-inf gives +inf gap -> no)
        if (M1 - M2 < GAP_THRESH) {
            const int slot = atomicAdd(counter, 1);
            if (slot < MAXSUS) suspects[slot] = b * HW + hw0 + t;
        }
    }
    __syncthreads();

    // pass 2: softmax denominator and weighted sum
    {
        const float M1 = finm[j];
        float se = 0.f, sw = 0.f;
        const int p0 = g * 32;
        for (int p = p0; p < p0 + 32; ++p) {
            if (validLds[p]) {
                const float d = dists[j][p];
                const float e = expf(d - M1);
                se += e; sw = fmaf(e, d, sw);
            }
        }
        redA[j][g] = se; redB[j][g] = sw;
    }
    __syncthreads();
    if (t < J) {
        float SE = 0.f, SW = 0.f;
#pragma unroll
        for (int gg = 0; gg < 8; ++gg) { SE += redA[t][gg]; SW += redB[t][gg]; }
        out[b * HW + hw0 + t] = SW / SE;
    }
}

// ---------------------------------------------------------------------------
// Recheck: exact fp64 argmax for near-tie positions (positive per-position
// scale cannot change ordering, so raw q . pn64 suffices). One block per
// suspect, one thread per proto, first-occurrence tie-break like jnp.argmax.
// ---------------------------------------------------------------------------
__global__ __launch_bounds__(256)
void recheck_kernel(const float* __restrict__ qry, const double* __restrict__ pn64,
                    const int* __restrict__ valid, const int* __restrict__ counter,
                    const int* __restrict__ suspects, float* __restrict__ out)
{
    __shared__ double rd[256];
    __shared__ int    ri[256];
    const int t = threadIdx.x;
    int n = *counter;
    if (n > MAXSUS) n = MAXSUS;

    for (int i = blockIdx.x; i < n; i += gridDim.x) {
        const int pos = suspects[i];
        const int b  = pos >> 12;
        const int hw = pos & (HW - 1);
        const float*  q  = qry + (size_t)b * C * HW + hw;
        const double* pr = pn64 + (size_t)t * C;
        double acc = 0.0;
#pragma unroll 8
        for (int c = 0; c < C; ++c) acc = fma((double)q[(size_t)c * HW], pr[c], acc);
        rd[t] = valid[t] ? acc : -INFINITY;
        ri[t] = t;
        __syncthreads();
        for (int off = 128; off > 0; off >>= 1) {
            if (t < off) {
                const double dv = rd[t + off]; const int iv = ri[t + off];
                if (dv > rd[t] || (dv == rd[t] && iv < ri[t])) { rd[t] = dv; ri[t] = iv; }
            }
            __syncthreads();
        }
        if (t == 0) out[OUT_ASSIGN + pos] = (float)ri[0];
        __syncthreads();
    }
}

// ---------------------------------------------------------------------------
extern "C" void kernel_launch(void* const* d_in, const int* in_sizes, int n_in,
                              void* d_out, int out_size, void* d_ws, size_t ws_size,
                              hipStream_t stream)
{
    const float* qry   = (const float*)d_in[0];
    const float* sup_x = (const float*)d_in[1];
    const float* sup_y = (const float*)d_in[2];
    float* out = (float*)d_out;
    char*  ws  = (char*)d_ws;

    // ws layout (~1.03 MiB total)
    float*  pnT      = (float*)(ws);                    // 256 KiB  pnT[c][p]
    double* pn64     = (double*)(ws + 256 * 1024);      // 512 KiB  pn64[p][c]
    int*    valid    = (int*)(ws + 768 * 1024);         // 1 KiB
    int*    counter  = (int*)(ws + 768 * 1024 + 1024);  // 4 B
    int*    suspects = (int*)(ws + 768 * 1024 + 2048);  // 256 KiB

    prep_kernel<<<dim3(P), dim3(256), 0, stream>>>(sup_x, sup_y, out, pnT, pn64, valid, counter);
    dist_kernel<<<dim3(BQ * (HW / 32)), dim3(256), 0, stream>>>(qry, pnT, valid, out, counter, suspects);
    recheck_kernel<<<dim3(256), dim3(256), 0, stream>>>(qry, pn64, valid, counter, suspects, out);
}

// Round 2
// 509.086 us; speedup vs baseline: 1.6279x; 1.6279x over previous
//
#include <hip/hip_runtime.h>
#include <math.h>

// Problem constants
constexpr int BQ = 32;       // query batch
constexpr int C  = 256;      // channels
constexpr int HW = 4096;     // 64*64
constexpr int W  = 64;
constexpr int P  = 256;      // protos (4 * 8 * 8)
constexpr float THRESH = 0.95f;
constexpr float SCALE  = 20.0f;
constexpr float EPSF   = 1e-4f;
constexpr double EPSD  = 1e-4;
constexpr float GAP_THRESH = 4e-3f;   // fp32 dist noise ~2e-5 -> 130x margin
constexpr int MAXSUS = 65536;

// d_out layout: pred [0, 131072) | debug_assign [131072, 262144) | proto_grid [262144, 278528)
constexpr int OUT_ASSIGN = BQ * HW;
constexpr int OUT_GRID   = 2 * BQ * HW;

// ---------------------------------------------------------------------------
// Prep: pooled protos (fp64 normalize), valid flags, proto_grid output,
// zero suspect counter. One block per proto, one thread per channel.
// ---------------------------------------------------------------------------
__global__ __launch_bounds__(256)
void prep_kernel(const float* __restrict__ sup_x, const float* __restrict__ sup_y,
                 float* __restrict__ out, float* __restrict__ pnT,
                 double* __restrict__ pn64, int* __restrict__ valid,
                 int* __restrict__ counter)
{
    const int p = blockIdx.x;     // proto index = s*64 + gy*8 + gx
    const int t = threadIdx.x;    // channel
    const int s = p >> 6, gy = (p >> 3) & 7, gx = p & 7;

    const float* base = sup_x + ((size_t)(s * C + t)) * HW + (gy * 8) * W + gx * 8;
    double sum = 0.0;
#pragma unroll
    for (int r = 0; r < 8; ++r) {
        const float4 a = *(const float4*)(base + r * W);
        const float4 bq = *(const float4*)(base + r * W + 4);
        // same accumulation order as the verified scalar version
        sum += (double)a.x;  sum += (double)a.y;  sum += (double)a.z;  sum += (double)a.w;
        sum += (double)bq.x; sum += (double)bq.y; sum += (double)bq.z; sum += (double)bq.w;
    }
    const double mean = sum * (1.0 / 64.0);

    __shared__ double red[256];
    red[t] = mean * mean;
    __syncthreads();
    for (int off = 128; off > 0; off >>= 1) {
        if (t < off) red[t] += red[t + off];
        __syncthreads();
    }
    const double nrm = sqrt(red[0]);
    const double pnv = mean / fmax(nrm, EPSD);
    pnT[t * P + p] = (float)pnv;            // transposed fp32 copy: pnT[c][p]
    pn64[(size_t)p * C + t] = pnv;          // fp64 copy: pn64[p][c]

    bool mybit = false;
    if (t < 64) {
        const int r = t >> 3, k = t & 7;
        mybit = sup_y[s * HW + (gy * 8 + r) * W + gx * 8 + k] > THRESH;
    }
    const unsigned long long bm = __ballot(mybit);   // wave 0 carries t=0..63
    if (t == 0) {
        valid[p] = (__popcll(bm) > 32) ? 1 : 0;      // mask_pooled > 0.5
        if (p == 0) *counter = 0;
    }
    // proto_grid output = mask_bin, flat order; block p covers 64 pixels
    if (t < 64) {
        const int i = p * 64 + t;
        out[OUT_GRID + i] = (sup_y[i] > THRESH) ? 1.0f : 0.0f;
    }
}

// ---------------------------------------------------------------------------
// Main: register-tiled fp32 dists + fused softmax/argmax/pred.
// 32 positions per block; thread tile = 8 positions x 4 protos.
// Wave jg owns positions jg*8..jg*8+7; lane pg owns protos 4pg..4pg+3,
// so per-position reductions are full-wave shuffle butterflies.
// LDS ~51 KiB -> 3 blocks/CU (12 waves/CU).
// ---------------------------------------------------------------------------
__global__ __launch_bounds__(256, 3)
void dist_kernel(const float* __restrict__ qry, const float* __restrict__ pnT,
                 const int* __restrict__ valid, float* __restrict__ out,
                 int* __restrict__ counter, int* __restrict__ suspects)
{
    constexpr int J  = 32;          // positions per block
    constexpr int CC = 16;          // channels per proto chunk
    constexpr int NCH = C / CC;     // 16 chunks

    __shared__ float qs[C][J];      // 32 KiB, q tile (raw, unnormalized)
    __shared__ float pnc[CC * P];   // 16 KiB, proto chunk [cc][p]
    __shared__ float redA[J][8];    // 1 KiB, ||q|| partials
    __shared__ float scale_s[J];
    __shared__ int   validLds[P];

    const int t    = threadIdx.x;
    const int b    = blockIdx.x >> 7;
    const int hw0  = (blockIdx.x & 127) * J;
    const int lane = t & 63;        // pg: protos 4*lane..4*lane+3
    const int jg   = t >> 6;        // wave: positions jg*8..jg*8+7
    const float* qb = qry + (size_t)b * C * HW + hw0;

    validLds[t] = valid[t];

    // stage q tile: float4, coalesced 128B segments per channel row
    {
        const int j4 = (t & 7) * 4;
        const int c0 = t >> 3;
#pragma unroll
        for (int it = 0; it < 8; ++it) {
            const int c = c0 + it * 32;
            const float4 v = *(const float4*)(qb + (size_t)c * HW + j4);
            qs[c][j4 + 0] = v.x; qs[c][j4 + 1] = v.y;
            qs[c][j4 + 2] = v.z; qs[c][j4 + 3] = v.w;
        }
    }
    __syncthreads();

    // per-position scale = 20 / max(||q||, eps) (one-time; bank conflicts ok)
    {
        const int j = t >> 3, part = t & 7;
        float ss = 0.f;
        for (int c = part * 32; c < part * 32 + 32; ++c) {
            const float q = qs[c][j]; ss = fmaf(q, q, ss);
        }
        redA[j][part] = ss;
    }
    __syncthreads();
    if (t < J) {
        float ss = 0.f;
#pragma unroll
        for (int g = 0; g < 8; ++g) ss += redA[t][g];
        scale_s[t] = SCALE / fmaxf(sqrtf(ss), EPSF);
    }

    // valid bitmask for my 4 protos (validLds stable after first sync)
    int vm = 0;
#pragma unroll
    for (int v = 0; v < 4; ++v) vm |= validLds[lane * 4 + v] << v;

    float acc[8][4];
#pragma unroll
    for (int u = 0; u < 8; ++u)
#pragma unroll
        for (int v = 0; v < 4; ++v) acc[u][v] = 0.f;

    for (int chunk = 0; chunk < NCH; ++chunk) {
        __syncthreads();   // protect pnc readers of previous chunk (and scale_s write on iter 0)
        // stage proto chunk: 16 KiB = 1024 float4, 4 per thread, coalesced
        {
            const float4* src = (const float4*)(pnT + chunk * CC * P);
            float4* dst = (float4*)pnc;
#pragma unroll
            for (int i = 0; i < 4; ++i) dst[i * 256 + t] = src[i * 256 + t];
        }
        __syncthreads();

#pragma unroll 4
        for (int cc = 0; cc < CC; ++cc) {
            const int c = chunk * CC + cc;
            const float4 qa = *(const float4*)&qs[c][jg * 8];       // wave-uniform broadcast
            const float4 qc = *(const float4*)&qs[c][jg * 8 + 4];   // wave-uniform broadcast
            const float4 pv = *(const float4*)(pnc + cc * P + lane * 4); // full-row, conflict-free
            const float qv[8]  = {qa.x, qa.y, qa.z, qa.w, qc.x, qc.y, qc.z, qc.w};
            const float pvv[4] = {pv.x, pv.y, pv.z, pv.w};
#pragma unroll
            for (int u = 0; u < 8; ++u)
#pragma unroll
                for (int v = 0; v < 4; ++v)
                    acc[u][v] = fmaf(qv[u], pvv[v], acc[u][v]);
        }
    }

    // scale dists in-place (per-position positive factor)
#pragma unroll
    for (int u = 0; u < 8; ++u) {
        const float sc = scale_s[jg * 8 + u];
#pragma unroll
        for (int v = 0; v < 4; ++v) acc[u][v] *= sc;
    }

    // pass 1: max / argmax (first occurrence) / 2nd-max via wave butterflies
    float M1[8];
#pragma unroll
    for (int u = 0; u < 8; ++u) {
        float m1 = -INFINITY, m2 = -INFINITY; int id = 0x7fffffff;
#pragma unroll
        for (int v = 0; v < 4; ++v) {
            if (vm & (1 << v)) {
                const float dd = acc[u][v];
                if (dd > m1)      { m2 = m1; m1 = dd; id = lane * 4 + v; }
                else if (dd > m2) { m2 = dd; }
            }
        }
#pragma unroll
        for (int s = 1; s < 64; s <<= 1) {
            const float om1 = __shfl_xor(m1, s);
            const float om2 = __shfl_xor(m2, s);
            const int   oid = __shfl_xor(id, s);
            const float lo  = fminf(m1, om1);
            if (om1 > m1 || (om1 == m1 && oid < id)) id = oid;
            m1 = fmaxf(m1, om1);
            m2 = fmaxf(lo, fmaxf(m2, om2));
        }
        M1[u] = m1;
        if (lane == u) {
            out[OUT_ASSIGN + b * HW + hw0 + jg * 8 + u] = (float)id;
            if (m1 - m2 < GAP_THRESH) {   // near-tie -> exact fp64 recheck
                const int slot = atomicAdd(counter, 1);
                if (slot < MAXSUS) suspects[slot] = b * HW + hw0 + jg * 8 + u;
            }
        }
    }

    // pass 2: softmax denominator and weighted sum
#pragma unroll
    for (int u = 0; u < 8; ++u) {
        float se = 0.f, sw = 0.f;
#pragma unroll
        for (int v = 0; v < 4; ++v) {
            if (vm & (1 << v)) {
                const float dd = acc[u][v];
                const float e = expf(dd - M1[u]);
                se += e; sw = fmaf(e, dd, sw);
            }
        }
#pragma unroll
        for (int s = 1; s < 64; s <<= 1) {
            se += __shfl_xor(se, s);
            sw += __shfl_xor(sw, s);
        }
        if (lane == u) out[b * HW + hw0 + jg * 8 + u] = sw / se;
    }
}

// ---------------------------------------------------------------------------
// Recheck: exact fp64 argmax for near-tie positions (positive per-position
// scale cannot change ordering, so raw q . pn64 suffices). One block per
// suspect, one thread per proto, first-occurrence tie-break like jnp.argmax.
// ---------------------------------------------------------------------------
__global__ __launch_bounds__(256)
void recheck_kernel(const float* __restrict__ qry, const double* __restrict__ pn64,
                    const int* __restrict__ valid, const int* __restrict__ counter,
                    const int* __restrict__ suspects, float* __restrict__ out)
{
    __shared__ double rd[256];
    __shared__ int    ri[256];
    const int t = threadIdx.x;
    int n = *counter;
    if (n > MAXSUS) n = MAXSUS;

    for (int i = blockIdx.x; i < n; i += gridDim.x) {
        const int pos = suspects[i];
        const int b  = pos >> 12;
        const int hw = pos & (HW - 1);
        const float*  q  = qry + (size_t)b * C * HW + hw;
        const double* pr = pn64 + (size_t)t * C;
        double acc = 0.0;
#pragma unroll 8
        for (int c = 0; c < C; ++c) acc = fma((double)q[(size_t)c * HW], pr[c], acc);
        rd[t] = valid[t] ? acc : -INFINITY;
        ri[t] = t;
        __syncthreads();
        for (int off = 128; off > 0; off >>= 1) {
            if (t < off) {
                const double dv = rd[t + off]; const int iv = ri[t + off];
                if (dv > rd[t] || (dv == rd[t] && iv < ri[t])) { rd[t] = dv; ri[t] = iv; }
            }
            __syncthreads();
        }
        if (t == 0) out[OUT_ASSIGN + pos] = (float)ri[0];
        __syncthreads();
    }
}

// ---------------------------------------------------------------------------
extern "C" void kernel_launch(void* const* d_in, const int* in_sizes, int n_in,
                              void* d_out, int out_size, void* d_ws, size_t ws_size,
                              hipStream_t stream)
{
    const float* qry   = (const float*)d_in[0];
    const float* sup_x = (const float*)d_in[1];
    const float* sup_y = (const float*)d_in[2];
    float* out = (float*)d_out;
    char*  ws  = (char*)d_ws;

    // ws layout (~1.03 MiB total)
    float*  pnT      = (float*)(ws);                    // 256 KiB  pnT[c][p]
    double* pn64     = (double*)(ws + 256 * 1024);      // 512 KiB  pn64[p][c]
    int*    valid    = (int*)(ws + 768 * 1024);         // 1 KiB
    int*    counter  = (int*)(ws + 768 * 1024 + 1024);  // 4 B
    int*    suspects = (int*)(ws + 768 * 1024 + 2048);  // 256 KiB

    prep_kernel<<<dim3(P), dim3(256), 0, stream>>>(sup_x, sup_y, out, pnT, pn64, valid, counter);
    dist_kernel<<<dim3(BQ * (HW / 32)), dim3(256), 0, stream>>>(qry, pnT, valid, out, counter, suspects);
    recheck_kernel<<<dim3(256), dim3(256), 0, stream>>>(qry, pn64, valid, counter, suspects, out);
}

// Round 3
// 351.078 us; speedup vs baseline: 2.3606x; 1.4501x over previous
//
#include <hip/hip_runtime.h>
#include <math.h>

// Problem constants
constexpr int BQ = 32;       // query batch
constexpr int C  = 256;      // channels
constexpr int HW = 4096;     // 64*64
constexpr int W  = 64;
constexpr int P  = 256;      // protos (4 * 8 * 8)
constexpr float THRESH = 0.95f;
constexpr float SCALE  = 20.0f;
constexpr float EPSF   = 1e-4f;
constexpr double EPSD  = 1e-4;
constexpr float GAP_THRESH = 1e-2f;   // split-bf16 dist noise ~3e-4 -> 30x margin
constexpr int MAXSUS = 65536;

// d_out layout: pred [0, 131072) | debug_assign [131072, 262144) | proto_grid [262144, 278528)
constexpr int OUT_ASSIGN = BQ * HW;
constexpr int OUT_GRID   = 2 * BQ * HW;

typedef __attribute__((ext_vector_type(8))) short short8;
typedef __attribute__((ext_vector_type(4))) float floatx4;

static __device__ __forceinline__ unsigned short f2bf(float x) {
    unsigned u = __float_as_uint(x);
    u += 0x7FFFu + ((u >> 16) & 1u);     // round-to-nearest-even (no NaN inputs)
    return (unsigned short)(u >> 16);
}
static __device__ __forceinline__ float bf2f(unsigned short h) {
    return __uint_as_float(((unsigned)h) << 16);
}

// Fragment-order offset (ushort units): [pt][ks][h][lane][j], lane = quad*16 + idx,
// element j of lane <-> k = ks*32 + quad*8 + j. A and B use the IDENTICAL map, so
// any k-permutation cancels in the MFMA contraction.
#define FRAGOFF(tile, ks, h, lane) (((((tile) * 8 + (ks)) * 2 + (h)) * 64 + (lane)) * 8)

// ---------------------------------------------------------------------------
// Prep: pooled protos (fp64 normalize) -> split-bf16 frag-order pB + fp64 pn64,
// valid flags, proto_grid output, zero suspect counter. Block=proto, thread=channel.
// ---------------------------------------------------------------------------
__global__ __launch_bounds__(256)
void prep_kernel(const float* __restrict__ sup_x, const float* __restrict__ sup_y,
                 float* __restrict__ out, unsigned short* __restrict__ pB,
                 double* __restrict__ pn64, int* __restrict__ valid,
                 int* __restrict__ counter)
{
    const int p = blockIdx.x;     // proto index = s*64 + gy*8 + gx
    const int t = threadIdx.x;    // channel
    const int s = p >> 6, gy = (p >> 3) & 7, gx = p & 7;

    const float* base = sup_x + ((size_t)(s * C + t)) * HW + (gy * 8) * W + gx * 8;
    double sum = 0.0;
#pragma unroll
    for (int r = 0; r < 8; ++r) {
        const float4 a  = *(const float4*)(base + r * W);
        const float4 bq = *(const float4*)(base + r * W + 4);
        sum += (double)a.x;  sum += (double)a.y;  sum += (double)a.z;  sum += (double)a.w;
        sum += (double)bq.x; sum += (double)bq.y; sum += (double)bq.z; sum += (double)bq.w;
    }
    const double mean = sum * (1.0 / 64.0);

    __shared__ double red[256];
    red[t] = mean * mean;
    __syncthreads();
    for (int off = 128; off > 0; off >>= 1) {
        if (t < off) red[t] += red[t + off];
        __syncthreads();
    }
    const double nrm = sqrt(red[0]);
    const double pnv = mean / fmax(nrm, EPSD);
    pn64[(size_t)p * C + t] = pnv;

    // split-bf16 frag-order store: nt=p>>4, n-idx=p&15; ks=c>>5, quad=(c>>3)&3, j=c&7
    const float pnf = (float)pnv;
    const unsigned short phi = f2bf(pnf);
    const unsigned short plo = f2bf(pnf - bf2f(phi));
    const int nt = p >> 4, ks = t >> 5, lane = (((t >> 3) & 3) << 4) | (p & 15), j = t & 7;
    pB[FRAGOFF(nt, ks, 0, lane) + j] = phi;
    pB[FRAGOFF(nt, ks, 1, lane) + j] = plo;

    bool mybit = false;
    if (t < 64) {
        const int r = t >> 3, k = t & 7;
        mybit = sup_y[s * HW + (gy * 8 + r) * W + gx * 8 + k] > THRESH;
    }
    const unsigned long long bm = __ballot(mybit);   // wave 0 carries t=0..63
    if (t == 0) {
        valid[p] = (__popcll(bm) > 32) ? 1 : 0;      // mask_pooled > 0.5
        if (p == 0) *counter = 0;
    }
    if (t < 64) {
        const int i = p * 64 + t;
        out[OUT_GRID + i] = (sup_y[i] > THRESH) ? 1.0f : 0.0f;
    }
}

// ---------------------------------------------------------------------------
// Main: split-bf16 MFMA dists + fused softmax/argmax/pred.
// Block = 64 positions x 256 protos; wave w -> protos w*64..+63, all 64 positions.
// Per wave: 4 pos-tiles x 4 proto-tiles x 8 k-steps x (3 split mfma) = 384 mfma.
// q staged in frag order (conflict-free b128 writes); B-frags read global->VGPR
// (L2-resident, coalesced) -> ZERO barriers inside the k-loop.
// ---------------------------------------------------------------------------
__global__ __launch_bounds__(256, 2)
void dist_kernel(const float* __restrict__ qry, const unsigned short* __restrict__ pB,
                 const int* __restrict__ valid, float* __restrict__ out,
                 int* __restrict__ counter, int* __restrict__ suspects)
{
    __shared__ unsigned short qs[4 * 8 * 2 * 64 * 8];  // 64 KiB frag-order q tile
    __shared__ float scale_lds[64];
    __shared__ int   validLds[P];
    __shared__ float pm1[4][64], pm2[4][64], pse[4][64], psw[4][64];
    __shared__ int   pid[4][64];
    __shared__ float M1s[64];

    const int t    = threadIdx.x;
    const int w    = t >> 6;      // wave: protos w*64..w*64+63
    const int l    = t & 63;
    const int quad = l >> 4;
    const int m    = l & 15;

    const int b    = blockIdx.x >> 6;
    const int pos0 = (blockIdx.x & 63) * 64;
    const float* qb = qry + (size_t)b * C * HW + pos0;

    validLds[t] = valid[t];

    // ---- stage q tile in frag order; wave w handles pos-tile pt=w ----
    // lane l covers pos = pos0 + w*16 + m, k = ks*32 + quad*8 + j
    float ssq = 0.f;
    {
        const float* qp = qb + w * 16 + m;
#pragma unroll 2
        for (int ks = 0; ks < 8; ++ks) {
            float v[8];
#pragma unroll
            for (int j = 0; j < 8; ++j)
                v[j] = qp[(size_t)(ks * 32 + quad * 8 + j) * HW];
            short8 h8, l8;
#pragma unroll
            for (int j = 0; j < 8; ++j) {
                ssq = fmaf(v[j], v[j], ssq);
                const unsigned short hi = f2bf(v[j]);
                h8[j] = (short)hi;
                l8[j] = (short)f2bf(v[j] - bf2f(hi));
            }
            *(short8*)&qs[FRAGOFF(w, ks, 0, l)] = h8;   // lane*16 B: conflict-free
            *(short8*)&qs[FRAGOFF(w, ks, 1, l)] = l8;
        }
    }
    // ||q||^2 for pos w*16+m: sum the 4 quads (lanes differing in bits 4,5)
    ssq += __shfl_xor(ssq, 16);
    ssq += __shfl_xor(ssq, 32);
    if (l < 16) scale_lds[w * 16 + l] = SCALE / fmaxf(sqrtf(ssq), EPSF);
    __syncthreads();   // qs + scale_lds + validLds ready; no more barriers until epilogue

    // ---- k-loop: 3-term split-bf16 MFMA, no barriers ----
    floatx4 acc[4][4];
#pragma unroll
    for (int pt = 0; pt < 4; ++pt)
#pragma unroll
        for (int v = 0; v < 4; ++v) acc[pt][v] = (floatx4){0.f, 0.f, 0.f, 0.f};

    for (int ks = 0; ks < 8; ++ks) {
        short8 bh[4], bl[4], ah[4], al[4];
#pragma unroll
        for (int v = 0; v < 4; ++v) {
            const unsigned short* bp = pB + FRAGOFF(w * 4 + v, ks, 0, l);
            bh[v] = *(const short8*)bp;          // coalesced 1 KiB, L2-hit
            bl[v] = *(const short8*)(bp + 512);  // h=1 plane
        }
#pragma unroll
        for (int pt = 0; pt < 4; ++pt) {
            ah[pt] = *(const short8*)&qs[FRAGOFF(pt, ks, 0, l)];
            al[pt] = *(const short8*)&qs[FRAGOFF(pt, ks, 1, l)];
        }
#pragma unroll
        for (int pt = 0; pt < 4; ++pt)
#pragma unroll
            for (int v = 0; v < 4; ++v) {
                acc[pt][v] = __builtin_amdgcn_mfma_f32_16x16x32_bf16(ah[pt], bh[v], acc[pt][v], 0, 0, 0);
                acc[pt][v] = __builtin_amdgcn_mfma_f32_16x16x32_bf16(ah[pt], bl[v], acc[pt][v], 0, 0, 0);
                acc[pt][v] = __builtin_amdgcn_mfma_f32_16x16x32_bf16(al[pt], bh[v], acc[pt][v], 0, 0, 0);
            }
    }

    // ---- epilogue. C/D layout: col = l&15 = proto-in-tile, row = quad*4 + r ----
    // scale dists in place (positive per-position factor, ordering-safe)
#pragma unroll
    for (int pt = 0; pt < 4; ++pt)
#pragma unroll
        for (int r = 0; r < 4; ++r) {
            const float sc = scale_lds[pt * 16 + quad * 4 + r];
#pragma unroll
            for (int v = 0; v < 4; ++v) acc[pt][v][r] *= sc;
        }

    int vld[4];
#pragma unroll
    for (int v = 0; v < 4; ++v) vld[v] = validLds[(w * 4 + v) * 16 + m];

    // stage 1: per-wave argmax/max/2nd-max over its 64 protos
#pragma unroll
    for (int pt = 0; pt < 4; ++pt)
#pragma unroll
        for (int r = 0; r < 4; ++r) {
            float m1 = -INFINITY, m2 = -INFINITY; int id = 0x7fffffff;
#pragma unroll
            for (int v = 0; v < 4; ++v) {
                if (vld[v]) {
                    const float d = acc[pt][v][r];
                    const int   n = (w * 4 + v) * 16 + m;
                    if (d > m1)      { m2 = m1; m1 = d; id = n; }
                    else if (d > m2) { m2 = d; }
                }
            }
#pragma unroll
            for (int sh = 1; sh < 16; sh <<= 1) {   // reduce over l&15 (protos)
                const float om1 = __shfl_xor(m1, sh);
                const float om2 = __shfl_xor(m2, sh);
                const int   oid = __shfl_xor(id, sh);
                if (om1 > m1) { m2 = fmaxf(m1, om2); m1 = om1; id = oid; }
                else { if (om1 == m1 && oid < id) id = oid; m2 = fmaxf(m2, om1); }
            }
            if (m == 0) {
                const int pos = pt * 16 + quad * 4 + r;
                pm1[w][pos] = m1; pm2[w][pos] = m2; pid[w][pos] = id;
            }
        }
    __syncthreads();

    // combine across waves (protos ascending in w -> first-occurrence ties OK)
    if (t < 64) {
        float M1 = -INFINITY, M2 = -INFINITY; int ID = 0x7fffffff;
#pragma unroll
        for (int ww = 0; ww < 4; ++ww) {
            const float a1 = pm1[ww][t], a2 = pm2[ww][t];
            const int   ai = pid[ww][t];
            if (a1 > M1) { M2 = fmaxf(M1, a2); M1 = a1; ID = ai; }
            else { if (a1 == M1 && ai < ID) ID = ai; M2 = fmaxf(M2, a1); }
        }
        M1s[t] = M1;
        const int posg = b * HW + pos0 + t;
        out[OUT_ASSIGN + posg] = (float)ID;
        if (M1 - M2 < GAP_THRESH) {           // near-tie -> exact fp64 recheck
            const int slot = atomicAdd(counter, 1);
            if (slot < MAXSUS) suspects[slot] = posg;
        }
    }
    __syncthreads();

    // stage 2: softmax partials per wave
#pragma unroll
    for (int pt = 0; pt < 4; ++pt)
#pragma unroll
        for (int r = 0; r < 4; ++r) {
            const float M = M1s[pt * 16 + quad * 4 + r];
            float se = 0.f, sw = 0.f;
#pragma unroll
            for (int v = 0; v < 4; ++v) {
                if (vld[v]) {
                    const float d = acc[pt][v][r];
                    const float e = expf(d - M);
                    se += e; sw = fmaf(e, d, sw);
                }
            }
#pragma unroll
            for (int sh = 1; sh < 16; sh <<= 1) {
                se += __shfl_xor(se, sh);
                sw += __shfl_xor(sw, sh);
            }
            if (m == 0) {
                const int pos = pt * 16 + quad * 4 + r;
                pse[w][pos] = se; psw[w][pos] = sw;
            }
        }
    __syncthreads();

    if (t < 64) {
        float SE = 0.f, SW = 0.f;
#pragma unroll
        for (int ww = 0; ww < 4; ++ww) { SE += pse[ww][t]; SW += psw[ww][t]; }
        out[b * HW + pos0 + t] = SW / SE;
    }
}

// ---------------------------------------------------------------------------
// Recheck: exact fp64 argmax for near-tie positions. Batches 16 suspects per
// block iteration: q columns staged to LDS once (parallel loads — kills the
// serialized stride-16KB HBM chain), protos streamed once per batch.
// First-occurrence tie-break like jnp.argmax.
// ---------------------------------------------------------------------------
__global__ __launch_bounds__(256)
void recheck_kernel(const float* __restrict__ qry, const double* __restrict__ pn64,
                    const int* __restrict__ valid, const int* __restrict__ counter,
                    const int* __restrict__ suspects, float* __restrict__ out)
{
    __shared__ float  qsh[16][256];
    __shared__ double pd[4];
    __shared__ int    pi[4];
    const int t = threadIdx.x;
    const int w = t >> 6, l = t & 63;
    int n = *counter; if (n > MAXSUS) n = MAXSUS;
    const int nb = (n + 15) >> 4;

    for (int batch = blockIdx.x; batch < nb; batch += gridDim.x) {
        const int base = batch * 16;
        const int cnt = (n - base < 16) ? (n - base) : 16;
        for (int s = 0; s < cnt; ++s) {
            const int pos = suspects[base + s];
            qsh[s][t] = qry[(size_t)(pos >> 12) * (C * HW) + (size_t)t * HW + (pos & (HW - 1))];
        }
        __syncthreads();

        double acc[16];
#pragma unroll
        for (int s = 0; s < 16; ++s) acc[s] = 0.0;
        const double* pr = pn64 + (size_t)t * C;   // thread t = proto t
#pragma unroll 4
        for (int c = 0; c < C; ++c) {
            const double pv = pr[c];
#pragma unroll
            for (int s = 0; s < 16; ++s) acc[s] = fma((double)qsh[s][c], pv, acc[s]);
        }
        const bool vl = valid[t] != 0;
        for (int s = 0; s < cnt; ++s) {
            double dv = vl ? acc[s] : -INFINITY;
            int id = t;
#pragma unroll
            for (int sh = 1; sh < 64; sh <<= 1) {
                const double od = __shfl_xor(dv, sh);
                const int    oi = __shfl_xor(id, sh);
                if (od > dv || (od == dv && oi < id)) { dv = od; id = oi; }
            }
            if (l == 0) { pd[w] = dv; pi[w] = id; }
            __syncthreads();
            if (t == 0) {
                double bd = pd[0]; int bi = pi[0];
                for (int ww = 1; ww < 4; ++ww)
                    if (pd[ww] > bd || (pd[ww] == bd && pi[ww] < bi)) { bd = pd[ww]; bi = pi[ww]; }
                out[OUT_ASSIGN + suspects[base + s]] = (float)bi;
            }
            __syncthreads();
        }
    }
}

// ---------------------------------------------------------------------------
extern "C" void kernel_launch(void* const* d_in, const int* in_sizes, int n_in,
                              void* d_out, int out_size, void* d_ws, size_t ws_size,
                              hipStream_t stream)
{
    const float* qry   = (const float*)d_in[0];
    const float* sup_x = (const float*)d_in[1];
    const float* sup_y = (const float*)d_in[2];
    float* out = (float*)d_out;
    char*  ws  = (char*)d_ws;

    // ws layout (~1.03 MiB total)
    unsigned short* pB       = (unsigned short*)(ws);   // 256 KiB frag-order split-bf16 protos
    double*         pn64     = (double*)(ws + 256 * 1024);       // 512 KiB
    int*            valid    = (int*)(ws + 768 * 1024);          // 1 KiB
    int*            counter  = (int*)(ws + 768 * 1024 + 1024);   // 4 B
    int*            suspects = (int*)(ws + 768 * 1024 + 2048);   // 256 KiB

    prep_kernel<<<dim3(P), dim3(256), 0, stream>>>(sup_x, sup_y, out, pB, pn64, valid, counter);
    dist_kernel<<<dim3(BQ * (HW / 64)), dim3(256), 0, stream>>>(qry, pB, valid, out, counter, suspects);
    recheck_kernel<<<dim3(256), dim3(256), 0, stream>>>(qry, pn64, valid, counter, suspects, out);
}

// Round 5
// 348.605 us; speedup vs baseline: 2.3774x; 1.0071x over previous
//
#include <hip/hip_runtime.h>
#include <math.h>

// Problem constants
constexpr int BQ = 32;       // query batch
constexpr int C  = 256;      // channels
constexpr int HW = 4096;     // 64*64
constexpr int W  = 64;
constexpr int P  = 256;      // protos (4 * 8 * 8)
constexpr float THRESH = 0.95f;
constexpr float SCALE  = 20.0f;
constexpr float EPSF   = 1e-4f;
constexpr double EPSD  = 1e-4;
constexpr float GAP_THRESH = 2e-3f;   // split-bf16 dist err ~5e-4 -> 4x margin
constexpr int MAXSUS = 65536;

// d_out layout: pred [0, 131072) | debug_assign [131072, 262144) | proto_grid [262144, 278528)
constexpr int OUT_ASSIGN = BQ * HW;
constexpr int OUT_GRID   = 2 * BQ * HW;

typedef __attribute__((ext_vector_type(8))) short short8;
typedef __attribute__((ext_vector_type(4))) float floatx4;

static __device__ __forceinline__ unsigned short f2bf(float x) {
    unsigned u = __float_as_uint(x);
    u += 0x7FFFu + ((u >> 16) & 1u);     // round-to-nearest-even (no NaN inputs)
    return (unsigned short)(u >> 16);
}
static __device__ __forceinline__ float bf2f(unsigned short h) {
    return __uint_as_float(((unsigned)h) << 16);
}

// Fragment-order offset (ushort units): [tile][ks][h][lane][j], lane = quad*16 + idx,
// element j of lane <-> k = ks*32 + quad*8 + j. A and B use the IDENTICAL map, so
// any k-permutation cancels in the MFMA contraction.
#define FRAGOFF(tile, ks, h, lane) (((((tile) * 8 + (ks)) * 2 + (h)) * 64 + (lane)) * 8)

// async global->LDS, 16 B/lane; LDS dest = wave-uniform base + lane*16
static __device__ __forceinline__ void gl_lds16(const unsigned short* gp, unsigned short* lp) {
    __builtin_amdgcn_global_load_lds(
        (const __attribute__((address_space(1))) unsigned int*)gp,
        (__attribute__((address_space(3))) unsigned int*)lp, 16, 0, 0);
}

// ---------------------------------------------------------------------------
// Prep: pooled protos (fp64 normalize) -> split-bf16 frag-order pB + fp64 pn64,
// valid flags, proto_grid output, zero suspect counter. Block=proto, thread=channel.
// ---------------------------------------------------------------------------
__global__ __launch_bounds__(256)
void prep_kernel(const float* __restrict__ sup_x, const float* __restrict__ sup_y,
                 float* __restrict__ out, unsigned short* __restrict__ pB,
                 double* __restrict__ pn64, int* __restrict__ valid,
                 int* __restrict__ counter)
{
    const int p = blockIdx.x;     // proto index = s*64 + gy*8 + gx
    const int t = threadIdx.x;    // channel
    const int s = p >> 6, gy = (p >> 3) & 7, gx = p & 7;

    const float* base = sup_x + ((size_t)(s * C + t)) * HW + (gy * 8) * W + gx * 8;
    double sum = 0.0;
#pragma unroll
    for (int r = 0; r < 8; ++r) {
        const float4 a  = *(const float4*)(base + r * W);
        const float4 bq = *(const float4*)(base + r * W + 4);
        sum += (double)a.x;  sum += (double)a.y;  sum += (double)a.z;  sum += (double)a.w;
        sum += (double)bq.x; sum += (double)bq.y; sum += (double)bq.z; sum += (double)bq.w;
    }
    const double mean = sum * (1.0 / 64.0);

    __shared__ double red[256];
    red[t] = mean * mean;
    __syncthreads();
    for (int off = 128; off > 0; off >>= 1) {
        if (t < off) red[t] += red[t + off];
        __syncthreads();
    }
    const double nrm = sqrt(red[0]);
    const double pnv = mean / fmax(nrm, EPSD);
    pn64[(size_t)p * C + t] = pnv;

    // split-bf16 frag-order store: nt=p>>4, n-idx=p&15; ks=c>>5, quad=(c>>3)&3, j=c&7
    const float pnf = (float)pnv;
    const unsigned short phi = f2bf(pnf);
    const unsigned short plo = f2bf(pnf - bf2f(phi));
    const int nt = p >> 4, ks = t >> 5, lane = (((t >> 3) & 3) << 4) | (p & 15), j = t & 7;
    pB[FRAGOFF(nt, ks, 0, lane) + j] = phi;
    pB[FRAGOFF(nt, ks, 1, lane) + j] = plo;

    bool mybit = false;
    if (t < 64) {
        const int r = t >> 3, k = t & 7;
        mybit = sup_y[s * HW + (gy * 8 + r) * W + gx * 8 + k] > THRESH;
    }
    const unsigned long long bm = __ballot(mybit);   // wave 0 carries t=0..63
    if (t == 0) {
        valid[p] = (__popcll(bm) > 32) ? 1 : 0;      // mask_pooled > 0.5
        if (p == 0) *counter = 0;
    }
    if (t < 64) {
        const int i = p * 64 + t;
        out[OUT_GRID + i] = (sup_y[i] > THRESH) ? 1.0f : 0.0f;
    }
}

// ---------------------------------------------------------------------------
// Main: split-bf16 MFMA dists + fused softmax/argmax/pred.
// Block = 64 positions (4 waves); wave w owns pos-tile w (16 pos) x ALL 256 protos.
// A-frags (own q, hi+lo, full K) live in REGISTERS for the whole k-loop (64 VGPRs).
// B staged per-ks into 32 KiB LDS via async global_load_lds; k-loop reads are
// short-latency ds_read_b128 only. Epilogue is wave-local (no cross-wave combine).
// 3 blocks/CU (LDS 33 KiB, VGPR <=170 via launch_bounds).
// ---------------------------------------------------------------------------
__global__ __launch_bounds__(256, 3)
void dist_kernel(const float* __restrict__ qry, const unsigned short* __restrict__ pB,
                 const int* __restrict__ valid, float* __restrict__ out,
                 int* __restrict__ counter, int* __restrict__ suspects)
{
    __shared__ unsigned short ldsB[16 * 2 * 64 * 8];   // 32 KiB: [nt][h][lane][j]
    __shared__ float scale_lds[64];
    __shared__ int   validLds[P];

    const int t    = threadIdx.x;
    const int w    = t >> 6;      // wave -> pos-tile
    const int l    = t & 63;
    const int quad = l >> 4;
    const int m    = l & 15;

    const int b    = blockIdx.x >> 6;
    const int pos0 = (blockIdx.x & 63) * 64;

    validLds[t] = valid[t];

    // ---- A staging: own pos-tile, full K, into registers (no barrier needed) ----
    // lane l covers pos = pos0 + w*16 + m, k = ks*32 + quad*8 + j
    short8 ah[8], al[8];
    float ssq = 0.f;
    {
        const float* qp = qry + (size_t)b * C * HW + pos0 + w * 16 + m;
#pragma unroll
        for (int ks = 0; ks < 8; ++ks) {
            float v[8];
#pragma unroll
            for (int j = 0; j < 8; ++j)
                v[j] = qp[(size_t)(ks * 32 + quad * 8 + j) * HW];
            short8 h8, l8;
#pragma unroll
            for (int j = 0; j < 8; ++j) {
                ssq = fmaf(v[j], v[j], ssq);
                const unsigned short hi = f2bf(v[j]);
                h8[j] = (short)hi;
                l8[j] = (short)f2bf(v[j] - bf2f(hi));
            }
            ah[ks] = h8; al[ks] = l8;
        }
    }
    // ||q||^2 for pos w*16+m: sum the 4 quads (lanes differing in bits 4,5)
    ssq += __shfl_xor(ssq, 16);
    ssq += __shfl_xor(ssq, 32);
    if (l < 16) scale_lds[w * 16 + l] = SCALE / fmaxf(sqrtf(ssq), EPSF);

    // ---- k-loop: stage B chunk to LDS (async), 48 MFMA per ks ----
    floatx4 acc[16];
#pragma unroll
    for (int nt = 0; nt < 16; ++nt) acc[nt] = (floatx4){0.f, 0.f, 0.f, 0.f};

#pragma unroll
    for (int ks = 0; ks < 8; ++ks) {
        __syncthreads();                 // previous chunk's readers done
        // 32 chunks of 1 KiB; wave w stages chunks w*8..w*8+7
#pragma unroll
        for (int i = 0; i < 8; ++i) {
            const int idx = w * 8 + i, nt = idx >> 1, h = idx & 1;
            gl_lds16(pB + FRAGOFF(nt, ks, h, 0) + l * 8,
                     &ldsB[(nt * 2 + h) * 512]);
        }
        __syncthreads();                 // vmcnt drained -> B chunk visible
#pragma unroll
        for (int nt = 0; nt < 16; ++nt) {
            const short8 bh = *(const short8*)&ldsB[((nt * 2 + 0) * 64 + l) * 8];
            const short8 bl = *(const short8*)&ldsB[((nt * 2 + 1) * 64 + l) * 8];
            acc[nt] = __builtin_amdgcn_mfma_f32_16x16x32_bf16(ah[ks], bh, acc[nt], 0, 0, 0);
            acc[nt] = __builtin_amdgcn_mfma_f32_16x16x32_bf16(ah[ks], bl, acc[nt], 0, 0, 0);
            acc[nt] = __builtin_amdgcn_mfma_f32_16x16x32_bf16(al[ks], bh, acc[nt], 0, 0, 0);
        }
    }

    // ---- epilogue (wave-local). C/D: proto = nt*16 + m, pos-in-tile = quad*4 + r ----
    int vbits = 0;
#pragma unroll
    for (int nt = 0; nt < 16; ++nt) vbits |= validLds[nt * 16 + m] << nt;

    float scr[4];
#pragma unroll
    for (int r = 0; r < 4; ++r) scr[r] = scale_lds[w * 16 + quad * 4 + r];
#pragma unroll
    for (int nt = 0; nt < 16; ++nt)
#pragma unroll
        for (int r = 0; r < 4; ++r) acc[nt][r] *= scr[r];   // positive factor: ordering-safe

#pragma unroll
    for (int r = 0; r < 4; ++r) {
        // pass 1: max / argmax (first occurrence) / 2nd-max
        float m1 = -INFINITY, m2 = -INFINITY; int id = 0x7fffffff;
#pragma unroll
        for (int nt = 0; nt < 16; ++nt) {
            if (vbits & (1 << nt)) {
                const float d = acc[nt][r];
                if (d > m1)      { m2 = m1; m1 = d; id = nt * 16 + m; }
                else if (d > m2) { m2 = d; }
            }
        }
#pragma unroll
        for (int sh = 1; sh < 16; sh <<= 1) {   // reduce over m (protos), within quad
            const float om1 = __shfl_xor(m1, sh);
            const float om2 = __shfl_xor(m2, sh);
            const int   oid = __shfl_xor(id, sh);
            if (om1 > m1) { m2 = fmaxf(m1, om2); m1 = om1; id = oid; }
            else { if (om1 == m1 && oid < id) id = oid; m2 = fmaxf(m2, om1); }
        }
        const int posg = b * HW + pos0 + w * 16 + quad * 4 + r;
        if (m == 0) {
            out[OUT_ASSIGN + posg] = (float)id;
            if (m1 - m2 < GAP_THRESH) {          // near-tie -> exact fp64 recheck
                const int slot = atomicAdd(counter, 1);
                if (slot < MAXSUS) suspects[slot] = posg;
            }
        }
        // pass 2: softmax denominator and weighted sum (all lanes hold m1)
        float se = 0.f, sw = 0.f;
#pragma unroll
        for (int nt = 0; nt < 16; ++nt) {
            if (vbits & (1 << nt)) {
                const float d = acc[nt][r];
                const float e = __expf(d - m1);
                se += e; sw = fmaf(e, d, sw);
            }
        }
#pragma unroll
        for (int sh = 1; sh < 16; sh <<= 1) {
            se += __shfl_xor(se, sh);
            sw += __shfl_xor(sw, sh);
        }
        if (m == 0) out[posg] = sw / se;
    }
}

// ---------------------------------------------------------------------------
// Recheck: exact fp64 argmax for near-tie positions. Batches 16 suspects per
// block iteration: q columns staged to LDS in parallel, protos streamed once
// per batch. First-occurrence tie-break like jnp.argmax.
// ---------------------------------------------------------------------------
__global__ __launch_bounds__(256)
void recheck_kernel(const float* __restrict__ qry, const double* __restrict__ pn64,
                    const int* __restrict__ valid, const int* __restrict__ counter,
                    const int* __restrict__ suspects, float* __restrict__ out)
{
    __shared__ float  qsh[16][256];
    __shared__ double pd[4];
    __shared__ int    pi[4];
    const int t = threadIdx.x;
    const int w = t >> 6, l = t & 63;
    int n = *counter; if (n > MAXSUS) n = MAXSUS;
    const int nb = (n + 15) >> 4;

    for (int batch = blockIdx.x; batch < nb; batch += gridDim.x) {
        const int base = batch * 16;
        const int cnt = (n - base < 16) ? (n - base) : 16;
        for (int s = 0; s < cnt; ++s) {
            const int pos = suspects[base + s];
            qsh[s][t] = qry[(size_t)(pos >> 12) * (C * HW) + (size_t)t * HW + (pos & (HW - 1))];
        }
        __syncthreads();

        double acc[16];
#pragma unroll
        for (int s = 0; s < 16; ++s) acc[s] = 0.0;
        const double* pr = pn64 + (size_t)t * C;   // thread t = proto t
#pragma unroll 4
        for (int c = 0; c < C; ++c) {
            const double pv = pr[c];
#pragma unroll
            for (int s = 0; s < 16; ++s) acc[s] = fma((double)qsh[s][c], pv, acc[s]);
        }
        const bool vl = valid[t] != 0;
        for (int s = 0; s < cnt; ++s) {
            double dv = vl ? acc[s] : -INFINITY;
            int id = t;
#pragma unroll
            for (int sh = 1; sh < 64; sh <<= 1) {
                const double od = __shfl_xor(dv, sh);
                const int    oi = __shfl_xor(id, sh);
                if (od > dv || (od == dv && oi < id)) { dv = od; id = oi; }
            }
            if (l == 0) { pd[w] = dv; pi[w] = id; }
            __syncthreads();
            if (t == 0) {
                double bd = pd[0]; int bi = pi[0];
                for (int ww = 1; ww < 4; ++ww)
                    if (pd[ww] > bd || (pd[ww] == bd && pi[ww] < bi)) { bd = pd[ww]; bi = pi[ww]; }
                out[OUT_ASSIGN + suspects[base + s]] = (float)bi;
            }
            __syncthreads();
        }
    }
}

// ---------------------------------------------------------------------------
extern "C" void kernel_launch(void* const* d_in, const int* in_sizes, int n_in,
                              void* d_out, int out_size, void* d_ws, size_t ws_size,
                              hipStream_t stream)
{
    const float* qry   = (const float*)d_in[0];
    const float* sup_x = (const float*)d_in[1];
    const float* sup_y = (const float*)d_in[2];
    float* out = (float*)d_out;
    char*  ws  = (char*)d_ws;

    // ws layout (~1.03 MiB total)
    unsigned short* pB       = (unsigned short*)(ws);            // 256 KiB frag-order split-bf16 protos
    double*         pn64     = (double*)(ws + 256 * 1024);       // 512 KiB
    int*            valid    = (int*)(ws + 768 * 1024);          // 1 KiB
    int*            counter  = (int*)(ws + 768 * 1024 + 1024);   // 4 B
    int*            suspects = (int*)(ws + 768 * 1024 + 2048);   // 256 KiB

    prep_kernel<<<dim3(P), dim3(256), 0, stream>>>(sup_x, sup_y, out, pB, pn64, valid, counter);
    dist_kernel<<<dim3(BQ * (HW / 64)), dim3(256), 0, stream>>>(qry, pB, valid, out, counter, suspects);
    recheck_kernel<<<dim3(256), dim3(256), 0, stream>>>(qry, pn64, valid, counter, suspects, out);
}

// Round 6
// 321.766 us; speedup vs baseline: 2.5757x; 1.0834x over previous
//
#include <hip/hip_runtime.h>
#include <math.h>

// Problem constants
constexpr int BQ = 32;       // query batch
constexpr int C  = 256;      // channels
constexpr int HW = 4096;     // 64*64
constexpr int W  = 64;
constexpr int P  = 256;      // protos (4 * 8 * 8)
constexpr float THRESH = 0.95f;
constexpr float SCALE  = 20.0f;
constexpr float EPSF   = 1e-4f;
constexpr double EPSD  = 1e-4;
constexpr float GAP_THRESH = 2e-3f;   // split-bf16 dist err ~5e-4 -> 4x margin
constexpr int MAXSUS = 65536;

// d_out layout: pred [0, 131072) | debug_assign [131072, 262144) | proto_grid [262144, 278528)
constexpr int OUT_ASSIGN = BQ * HW;
constexpr int OUT_GRID   = 2 * BQ * HW;

typedef __attribute__((ext_vector_type(8))) short short8;
typedef __attribute__((ext_vector_type(4))) float floatx4;

static __device__ __forceinline__ unsigned short f2bf(float x) {
    unsigned u = __float_as_uint(x);
    u += 0x7FFFu + ((u >> 16) & 1u);     // round-to-nearest-even (no NaN inputs)
    return (unsigned short)(u >> 16);
}
static __device__ __forceinline__ float bf2f(unsigned short h) {
    return __uint_as_float(((unsigned)h) << 16);
}

// Fragment-order offset (ushort units): [tile][ks][h][lane][j], lane = quad*16 + idx,
// element j of lane <-> k = ks*32 + quad*8 + j. A and B use the IDENTICAL map, so
// any k-permutation cancels in the MFMA contraction.
#define FRAGOFF(tile, ks, h, lane) (((((tile) * 8 + (ks)) * 2 + (h)) * 64 + (lane)) * 8)

// async global->LDS, 16 B/lane; LDS dest = wave-uniform base + lane*16
static __device__ __forceinline__ void gl_lds16(const unsigned short* gp, unsigned short* lp) {
    __builtin_amdgcn_global_load_lds(
        (const __attribute__((address_space(1))) unsigned int*)gp,
        (__attribute__((address_space(3))) unsigned int*)lp, 16, 0, 0);
}

// ---------------------------------------------------------------------------
// Prep: pooled protos (fp64 normalize) -> split-bf16 frag-order pB + fp64 pn64,
// valid flags, proto_grid output, zero suspect counter. Block=proto, thread=channel.
// ---------------------------------------------------------------------------
__global__ __launch_bounds__(256)
void prep_kernel(const float* __restrict__ sup_x, const float* __restrict__ sup_y,
                 float* __restrict__ out, unsigned short* __restrict__ pB,
                 double* __restrict__ pn64, int* __restrict__ valid,
                 int* __restrict__ counter)
{
    const int p = blockIdx.x;     // proto index = s*64 + gy*8 + gx
    const int t = threadIdx.x;    // channel
    const int s = p >> 6, gy = (p >> 3) & 7, gx = p & 7;

    const float* base = sup_x + ((size_t)(s * C + t)) * HW + (gy * 8) * W + gx * 8;
    double sum = 0.0;
#pragma unroll
    for (int r = 0; r < 8; ++r) {
        const float4 a  = *(const float4*)(base + r * W);
        const float4 bq = *(const float4*)(base + r * W + 4);
        sum += (double)a.x;  sum += (double)a.y;  sum += (double)a.z;  sum += (double)a.w;
        sum += (double)bq.x; sum += (double)bq.y; sum += (double)bq.z; sum += (double)bq.w;
    }
    const double mean = sum * (1.0 / 64.0);

    __shared__ double red[256];
    red[t] = mean * mean;
    __syncthreads();
    for (int off = 128; off > 0; off >>= 1) {
        if (t < off) red[t] += red[t + off];
        __syncthreads();
    }
    const double nrm = sqrt(red[0]);
    const double pnv = mean / fmax(nrm, EPSD);
    pn64[(size_t)p * C + t] = pnv;

    // split-bf16 frag-order store: nt=p>>4, n-idx=p&15; ks=c>>5, quad=(c>>3)&3, j=c&7
    const float pnf = (float)pnv;
    const unsigned short phi = f2bf(pnf);
    const unsigned short plo = f2bf(pnf - bf2f(phi));
    const int nt = p >> 4, ks = t >> 5, lane = (((t >> 3) & 3) << 4) | (p & 15), j = t & 7;
    pB[FRAGOFF(nt, ks, 0, lane) + j] = phi;
    pB[FRAGOFF(nt, ks, 1, lane) + j] = plo;

    bool mybit = false;
    if (t < 64) {
        const int r = t >> 3, k = t & 7;
        mybit = sup_y[s * HW + (gy * 8 + r) * W + gx * 8 + k] > THRESH;
    }
    const unsigned long long bm = __ballot(mybit);   // wave 0 carries t=0..63
    if (t == 0) {
        valid[p] = (__popcll(bm) > 32) ? 1 : 0;      // mask_pooled > 0.5
        if (p == 0) *counter = 0;
    }
    if (t < 64) {
        const int i = p * 64 + t;
        out[OUT_GRID + i] = (sup_y[i] > THRESH) ? 1.0f : 0.0f;
    }
}

// ---------------------------------------------------------------------------
// Main: split-bf16 MFMA dists + fused softmax/argmax/pred.
// Block = 64 positions (4 waves); wave w owns pos-tile w (16 pos) x ALL 256 protos.
// A-frags (own q, hi+lo, full K) live in REGISTERS for the whole k-loop (64 VGPRs).
// B staged per-ks into 32 KiB LDS via async global_load_lds; k-loop reads are
// short-latency ds_read_b128 only. Epilogue is wave-local (no cross-wave combine).
// launch_bounds(256,2): 256-reg/wave budget -> acc(64,AGPR)+ah/al(64)+temps fit
// WITHOUT spilling. (R5's (256,3) capped arch-VGPRs at 84 -> 64 regs/thread
// spilled to scratch -> 128 MB WRITE_SIZE, 267 MB HBM traffic, 203 us.)
// ---------------------------------------------------------------------------
__global__ __launch_bounds__(256, 2)
void dist_kernel(const float* __restrict__ qry, const unsigned short* __restrict__ pB,
                 const int* __restrict__ valid, float* __restrict__ out,
                 int* __restrict__ counter, int* __restrict__ suspects)
{
    __shared__ unsigned short ldsB[16 * 2 * 64 * 8];   // 32 KiB: [nt][h][lane][j]
    __shared__ float scale_lds[64];
    __shared__ int   validLds[P];

    const int t    = threadIdx.x;
    const int w    = t >> 6;      // wave -> pos-tile
    const int l    = t & 63;
    const int quad = l >> 4;
    const int m    = l & 15;

    const int b    = blockIdx.x >> 6;
    const int pos0 = (blockIdx.x & 63) * 64;

    validLds[t] = valid[t];

    // ---- A staging: own pos-tile, full K, into registers (no barrier needed) ----
    // lane l covers pos = pos0 + w*16 + m, k = ks*32 + quad*8 + j
    short8 ah[8], al[8];
    float ssq = 0.f;
    {
        const float* qp = qry + (size_t)b * C * HW + pos0 + w * 16 + m;
#pragma unroll
        for (int ks = 0; ks < 8; ++ks) {
            float v[8];
#pragma unroll
            for (int j = 0; j < 8; ++j)
                v[j] = qp[(size_t)(ks * 32 + quad * 8 + j) * HW];
            short8 h8, l8;
#pragma unroll
            for (int j = 0; j < 8; ++j) {
                ssq = fmaf(v[j], v[j], ssq);
                const unsigned short hi = f2bf(v[j]);
                h8[j] = (short)hi;
                l8[j] = (short)f2bf(v[j] - bf2f(hi));
            }
            ah[ks] = h8; al[ks] = l8;
        }
    }
    // ||q||^2 for pos w*16+m: sum the 4 quads (lanes differing in bits 4,5)
    ssq += __shfl_xor(ssq, 16);
    ssq += __shfl_xor(ssq, 32);
    if (l < 16) scale_lds[w * 16 + l] = SCALE / fmaxf(sqrtf(ssq), EPSF);

    // ---- k-loop: stage B chunk to LDS (async), 48 MFMA per ks ----
    floatx4 acc[16];
#pragma unroll
    for (int nt = 0; nt < 16; ++nt) acc[nt] = (floatx4){0.f, 0.f, 0.f, 0.f};

#pragma unroll
    for (int ks = 0; ks < 8; ++ks) {
        __syncthreads();                 // previous chunk's readers done
        // 32 chunks of 1 KiB; wave w stages chunks w*8..w*8+7
#pragma unroll
        for (int i = 0; i < 8; ++i) {
            const int idx = w * 8 + i, nt = idx >> 1, h = idx & 1;
            gl_lds16(pB + FRAGOFF(nt, ks, h, 0) + l * 8,
                     &ldsB[(nt * 2 + h) * 512]);
        }
        __syncthreads();                 // vmcnt drained -> B chunk visible
#pragma unroll
        for (int nt = 0; nt < 16; ++nt) {
            const short8 bh = *(const short8*)&ldsB[((nt * 2 + 0) * 64 + l) * 8];
            const short8 bl = *(const short8*)&ldsB[((nt * 2 + 1) * 64 + l) * 8];
            acc[nt] = __builtin_amdgcn_mfma_f32_16x16x32_bf16(ah[ks], bh, acc[nt], 0, 0, 0);
            acc[nt] = __builtin_amdgcn_mfma_f32_16x16x32_bf16(ah[ks], bl, acc[nt], 0, 0, 0);
            acc[nt] = __builtin_amdgcn_mfma_f32_16x16x32_bf16(al[ks], bh, acc[nt], 0, 0, 0);
        }
    }

    // ---- epilogue (wave-local). C/D: proto = nt*16 + m, pos-in-tile = quad*4 + r ----
    int vbits = 0;
#pragma unroll
    for (int nt = 0; nt < 16; ++nt) vbits |= validLds[nt * 16 + m] << nt;

    float scr[4];
#pragma unroll
    for (int r = 0; r < 4; ++r) scr[r] = scale_lds[w * 16 + quad * 4 + r];
#pragma unroll
    for (int nt = 0; nt < 16; ++nt)
#pragma unroll
        for (int r = 0; r < 4; ++r) acc[nt][r] *= scr[r];   // positive factor: ordering-safe

#pragma unroll
    for (int r = 0; r < 4; ++r) {
        // pass 1: max / argmax (first occurrence) / 2nd-max
        float m1 = -INFINITY, m2 = -INFINITY; int id = 0x7fffffff;
#pragma unroll
        for (int nt = 0; nt < 16; ++nt) {
            if (vbits & (1 << nt)) {
                const float d = acc[nt][r];
                if (d > m1)      { m2 = m1; m1 = d; id = nt * 16 + m; }
                else if (d > m2) { m2 = d; }
            }
        }
#pragma unroll
        for (int sh = 1; sh < 16; sh <<= 1) {   // reduce over m (protos), within quad
            const float om1 = __shfl_xor(m1, sh);
            const float om2 = __shfl_xor(m2, sh);
            const int   oid = __shfl_xor(id, sh);
            if (om1 > m1) { m2 = fmaxf(m1, om2); m1 = om1; id = oid; }
            else { if (om1 == m1 && oid < id) id = oid; m2 = fmaxf(m2, om1); }
        }
        const int posg = b * HW + pos0 + w * 16 + quad * 4 + r;
        if (m == 0) {
            out[OUT_ASSIGN + posg] = (float)id;
            if (m1 - m2 < GAP_THRESH) {          // near-tie -> exact fp64 recheck
                const int slot = atomicAdd(counter, 1);
                if (slot < MAXSUS) suspects[slot] = posg;
            }
        }
        // pass 2: softmax denominator and weighted sum (all lanes hold m1)
        float se = 0.f, sw = 0.f;
#pragma unroll
        for (int nt = 0; nt < 16; ++nt) {
            if (vbits & (1 << nt)) {
                const float d = acc[nt][r];
                const float e = __expf(d - m1);
                se += e; sw = fmaf(e, d, sw);
            }
        }
#pragma unroll
        for (int sh = 1; sh < 16; sh <<= 1) {
            se += __shfl_xor(se, sh);
            sw += __shfl_xor(sw, sh);
        }
        if (m == 0) out[posg] = sw / se;
    }
}

// ---------------------------------------------------------------------------
// Recheck: exact fp64 argmax for near-tie positions. Batches 16 suspects per
// block iteration: q columns staged to LDS in parallel, protos streamed once
// per batch. First-occurrence tie-break like jnp.argmax.
// ---------------------------------------------------------------------------
__global__ __launch_bounds__(256)
void recheck_kernel(const float* __restrict__ qry, const double* __restrict__ pn64,
                    const int* __restrict__ valid, const int* __restrict__ counter,
                    const int* __restrict__ suspects, float* __restrict__ out)
{
    __shared__ float  qsh[16][256];
    __shared__ double pd[4];
    __shared__ int    pi[4];
    const int t = threadIdx.x;
    const int w = t >> 6, l = t & 63;
    int n = *counter; if (n > MAXSUS) n = MAXSUS;
    const int nb = (n + 15) >> 4;

    for (int batch = blockIdx.x; batch < nb; batch += gridDim.x) {
        const int base = batch * 16;
        const int cnt = (n - base < 16) ? (n - base) : 16;
        for (int s = 0; s < cnt; ++s) {
            const int pos = suspects[base + s];
            qsh[s][t] = qry[(size_t)(pos >> 12) * (C * HW) + (size_t)t * HW + (pos & (HW - 1))];
        }
        __syncthreads();

        double acc[16];
#pragma unroll
        for (int s = 0; s < 16; ++s) acc[s] = 0.0;
        const double* pr = pn64 + (size_t)t * C;   // thread t = proto t
#pragma unroll 4
        for (int c = 0; c < C; ++c) {
            const double pv = pr[c];
#pragma unroll
            for (int s = 0; s < 16; ++s) acc[s] = fma((double)qsh[s][c], pv, acc[s]);
        }
        const bool vl = valid[t] != 0;
        for (int s = 0; s < cnt; ++s) {
            double dv = vl ? acc[s] : -INFINITY;
            int id = t;
#pragma unroll
            for (int sh = 1; sh < 64; sh <<= 1) {
                const double od = __shfl_xor(dv, sh);
                const int    oi = __shfl_xor(id, sh);
                if (od > dv || (od == dv && oi < id)) { dv = od; id = oi; }
            }
            if (l == 0) { pd[w] = dv; pi[w] = id; }
            __syncthreads();
            if (t == 0) {
                double bd = pd[0]; int bi = pi[0];
                for (int ww = 1; ww < 4; ++ww)
                    if (pd[ww] > bd || (pd[ww] == bd && pi[ww] < bi)) { bd = pd[ww]; bi = pi[ww]; }
                out[OUT_ASSIGN + suspects[base + s]] = (float)bi;
            }
            __syncthreads();
        }
    }
}

// ---------------------------------------------------------------------------
extern "C" void kernel_launch(void* const* d_in, const int* in_sizes, int n_in,
                              void* d_out, int out_size, void* d_ws, size_t ws_size,
                              hipStream_t stream)
{
    const float* qry   = (const float*)d_in[0];
    const float* sup_x = (const float*)d_in[1];
    const float* sup_y = (const float*)d_in[2];
    float* out = (float*)d_out;
    char*  ws  = (char*)d_ws;

    // ws layout (~1.03 MiB total)
    unsigned short* pB       = (unsigned short*)(ws);            // 256 KiB frag-order split-bf16 protos
    double*         pn64     = (double*)(ws + 256 * 1024);       // 512 KiB
    int*            valid    = (int*)(ws + 768 * 1024);          // 1 KiB
    int*            counter  = (int*)(ws + 768 * 1024 + 1024);   // 4 B
    int*            suspects = (int*)(ws + 768 * 1024 + 2048);   // 256 KiB

    prep_kernel<<<dim3(P), dim3(256), 0, stream>>>(sup_x, sup_y, out, pB, pn64, valid, counter);
    dist_kernel<<<dim3(BQ * (HW / 64)), dim3(256), 0, stream>>>(qry, pB, valid, out, counter, suspects);
    recheck_kernel<<<dim3(256), dim3(256), 0, stream>>>(qry, pn64, valid, counter, suspects, out);
}